// Round 15
// baseline (1787.518 us; speedup 1.0000x reference)
//
#include <hip/hip_runtime.h>
#include <hip/hip_bf16.h>
#include <hip/hip_cooperative_groups.h>

namespace cg = cooperative_groups;

#define D_MODEL 384
#define N_LAYER 4
#define VOCAB   5000
#define D_INNER 768
#define D_STATE 16
#define DT_RANK 24
#define D_CONV  4
#define BATCH   4
#define SEQ     2048
#define ROWS    (BATCH*SEQ)          // 8192
#define NCHUNK  64
#define CLEN    32                   // NCHUNK*CLEN == SEQ

typedef __attribute__((ext_vector_type(8))) short bf16x8;
typedef __attribute__((ext_vector_type(4))) float f32x4;

// fp32 -> bf16 (RNE), finite inputs only
static __device__ __forceinline__ ushort f2b(float f) {
    uint u = __float_as_uint(f);
    return (ushort)((u + 0x7FFFu + ((u >> 16) & 1u)) >> 16);
}
static __device__ __forceinline__ float b2f(ushort u) {
    return __uint_as_float((uint)u << 16);
}
// branchless softplus, hardware exp/log only (no libm call)
static __device__ __forceinline__ float softplus_f(float v) {
    return fmaxf(v, 0.f) + __logf(1.f + __expf(-fabsf(v)));
}

// async global->LDS, 16B per lane (dst = wave base + lane*16, linear)
static __device__ __forceinline__ void gl_lds16(const void* g, void* l) {
    __builtin_amdgcn_global_load_lds(
        (const __attribute__((address_space(1))) void*)g,
        (__attribute__((address_space(3))) void*)l, 16, 0, 0);
}

// s_waitcnt with vmcnt=N, lgkmcnt/expcnt = don't-care
template<int N> static __device__ __forceinline__ void waitcnt_vm() {
    __builtin_amdgcn_s_waitcnt((N & 0xF) | (7 << 4) | (0xF << 8) | (((N >> 4) & 3) << 14));
}

// ---------------------------------------------------------------- fused one-shot prep
// Jobs (flat index space):
//   [0, 589824)            : in_proj_w  f32x4 -> bf16x4
//   [589824, 884736)       : out_proj_w f32x4 -> bf16x4
//   [884736, 1364736)      : embed      f32x4 -> bf16x4
//   [1364736, 4117248)     : wf element (build fused proj weight)
//   [4117248, 4903680)     : embed gather -> x (float4 per job)
__global__ __launch_bounds__(256)
void prep_k(const float* __restrict__ inw, const float* __restrict__ outw,
            const float* __restrict__ emb, const float* __restrict__ xpw,
            const float* __restrict__ dtw, const int* __restrict__ tokens,
            ushort* __restrict__ inw_b, ushort* __restrict__ outw_b,
            ushort* __restrict__ emb_b, ushort* __restrict__ wf,
            float* __restrict__ x)
{
    int idx = blockIdx.x * 256 + threadIdx.x;
    if (idx < 589824) {
        float4 v = reinterpret_cast<const float4*>(inw)[idx];
        ushort4 o; o.x=f2b(v.x); o.y=f2b(v.y); o.z=f2b(v.z); o.w=f2b(v.w);
        reinterpret_cast<ushort4*>(inw_b)[idx] = o;
    } else if (idx < 884736) {
        int i = idx - 589824;
        float4 v = reinterpret_cast<const float4*>(outw)[i];
        ushort4 o; o.x=f2b(v.x); o.y=f2b(v.y); o.z=f2b(v.z); o.w=f2b(v.w);
        reinterpret_cast<ushort4*>(outw_b)[i] = o;
    } else if (idx < 1364736) {
        int i = idx - 884736;
        float4 v = reinterpret_cast<const float4*>(emb)[i];
        ushort4 o; o.x=f2b(v.x); o.y=f2b(v.y); o.z=f2b(v.z); o.w=f2b(v.w);
        reinterpret_cast<ushort4*>(emb_b)[i] = o;
    } else if (idx < 4117248) {
        int i = idx - 1364736;                      // 4*896*768 elements
        int l = i / (896*768); int rk = i % (896*768);
        int r = rk / 768, k = rk % 768;
        float v = 0.f;
        if (r < 768) {
            const float* dr = dtw + ((size_t)l*768 + r)*24;
            const float* xc = xpw + (size_t)l*56*768 + k;
            #pragma unroll
            for (int q = 0; q < 24; ++q) v += dr[q] * xc[(size_t)q*768];
        } else if (r < 800) {
            v = xpw[((size_t)l*56 + 24 + (r-768))*768 + k];
        }
        wf[i] = f2b(v);
    } else {
        int i = idx - 4117248;                      // ROWS*96 float4 jobs
        int row = i / 96, c4 = i % 96;
        int tok = tokens[row];
        reinterpret_cast<float4*>(x)[(size_t)row * 96 + c4] =
            reinterpret_cast<const float4*>(emb)[(size_t)tok * 96 + c4];
    }
}

// ---------------------------------------------------------------- rmsnorm -> bf16
__global__ __launch_bounds__(256)
void rmsnorm_k(const float* __restrict__ xin, const float* __restrict__ w,
               ushort* __restrict__ xout)
{
    int row  = blockIdx.x * 4 + (threadIdx.x >> 6);
    int lane = threadIdx.x & 63;
    const float* xr = xin + (size_t)row * D_MODEL;
    float v[6]; float ss = 0.f;
    #pragma unroll
    for (int j = 0; j < 6; ++j) { v[j] = xr[lane + 64*j]; ss += v[j]*v[j]; }
    #pragma unroll
    for (int m = 32; m; m >>= 1) ss += __shfl_xor(ss, m, 64);
    float r = rsqrtf(ss * (1.f/D_MODEL) + 1e-5f);
    ushort* yo = xout + (size_t)row * D_MODEL;
    #pragma unroll
    for (int j = 0; j < 6; ++j) yo[lane + 64*j] = f2b(v[j] * w[lane + 64*j] * r);
}

// ---------------------------------------------------------------- conv1d + silu -> bf16
// 4 channels per thread: ushort4 loads/stores, float4 weights.
__global__ __launch_bounds__(256)
void conv_silu_k(const ushort* __restrict__ xz_b, const float* __restrict__ cw,
                 const float* __restrict__ cb, ushort* __restrict__ xout_b)
{
    int idx = blockIdx.x * 256 + threadIdx.x;       // ROWS * 192
    int e4  = idx % 192;                            // quad of channels
    int row = idx / 192;
    int e   = e4 * 4;
    int l   = row & (SEQ - 1);

    float4 w0 = reinterpret_cast<const float4*>(cw)[e4*4 + 0];
    float4 w1 = reinterpret_cast<const float4*>(cw)[e4*4 + 1];
    float4 w2 = reinterpret_cast<const float4*>(cw)[e4*4 + 2];
    float4 w3 = reinterpret_cast<const float4*>(cw)[e4*4 + 3];
    float4 bv = reinterpret_cast<const float4*>(cb)[e4];
    float ac0 = bv.x, ac1 = bv.y, ac2 = bv.z, ac3 = bv.w;

    #pragma unroll
    for (int j = 0; j < 4; ++j) {
        if (l - j >= 0) {
            ushort4 v = *reinterpret_cast<const ushort4*>(
                &xz_b[(size_t)(row - j) * (2*D_INNER) + e]);
            float wj0 = (&w0.x)[3-j], wj1 = (&w1.x)[3-j],
                  wj2 = (&w2.x)[3-j], wj3 = (&w3.x)[3-j];
            ac0 += wj0 * b2f(v.x); ac1 += wj1 * b2f(v.y);
            ac2 += wj2 * b2f(v.z); ac3 += wj3 * b2f(v.w);
        }
    }
    ushort4 o;
    o.x = f2b(ac0 / (1.f + __expf(-ac0)));
    o.y = f2b(ac1 / (1.f + __expf(-ac1)));
    o.z = f2b(ac2 / (1.f + __expf(-ac2)));
    o.w = f2b(ac3 / (1.f + __expf(-ac3)));
    *reinterpret_cast<ushort4*>(&xout_b[(size_t)row * D_INNER + e]) = o;
}

// ---------------------------------------------------------------- LDS-staged MFMA GEMM
// C[M,N](f32) = A[M,K](bf16) @ B[N,K](bf16)^T.
// 3-buf counted-vmcnt pipeline; swapped-operand MFMA (lane holds C row m = l15,
// 4 consecutive cols); XOR-swizzled LDS (both-sides).
// EPI: 0 store f32x4 (C) | 2 C += (f32x4 RMW) | 4 store bf16x4 (Cb, ldc)
//      5 fused-proj: n<768 -> softplus(v+bias[n]) -> bf16x4 Cb (ldc=768) ;
//                    768<=n<800 -> f32x4 -> C[m*32 + n-768]  (bc buffer)
template<int TM, int TN, int EPI>
__global__ __launch_bounds__(256)
void gemm_lds(const ushort* __restrict__ A, int lda,
              const ushort* __restrict__ B, int ldb,
              float* __restrict__ C, int ldc,
              ushort* __restrict__ Cb, const float* __restrict__ bias,
              int N, int K)
{
    constexpr int FM = TM / 32, FN = TN / 32;
    constexpr int LPT = TM/64 + TN/64;
    __shared__ alignas(16) ushort As[3][TM * 32];
    __shared__ alignas(16) ushort Bs[3][TN * 32];
    int tid = threadIdx.x, w = tid >> 6, l = tid & 63;
    int wr = w >> 1, wc = w & 1;
    int row0 = blockIdx.y * TM, col0 = blockIdx.x * TN;
    int l15 = l & 15, g = l >> 4;
    int sr = l >> 2, sp = l & 3;

    f32x4 acc[FM][FN] = {};

    auto stage = [&](int buf, int k0) {
        #pragma unroll
        for (int j = 0; j < TM/64; ++j) {
            int ai = w * (TM/64) + j;
            int r  = ai * 16 + sr;
            int s  = sp ^ ((r >> 1) & 3);
            gl_lds16(&A[(size_t)(row0 + r) * lda + k0 + s*8], &As[buf][ai * 512]);
        }
        #pragma unroll
        for (int j = 0; j < TN/64; ++j) {
            int bi = w * (TN/64) + j;
            int r  = bi * 16 + sr;
            int s  = sp ^ ((r >> 1) & 3);
            gl_lds16(&B[(size_t)(col0 + r) * ldb + k0 + s*8], &Bs[buf][bi * 512]);
        }
    };

    int nk = K >> 5;
    stage(0, 0);
    if (nk > 1) stage(1, 32);

    int cur = 0, sbuf = 2;
    for (int t = 0; t < nk; ++t) {
        if (t < nk - 1) waitcnt_vm<LPT>();
        else            waitcnt_vm<0>();
        __builtin_amdgcn_sched_barrier(0);
        __builtin_amdgcn_s_barrier();
        __builtin_amdgcn_sched_barrier(0);
        if (t + 2 < nk) stage(sbuf, (t + 2) << 5);
        __builtin_amdgcn_sched_barrier(0);

        bf16x8 af[FM], bfr[FN];
        #pragma unroll
        for (int i = 0; i < FM; ++i) {
            int r = wr * (TM/2) + i*16 + l15;
            int p = g ^ ((r >> 1) & 3);
            af[i] = *reinterpret_cast<const bf16x8*>(&As[cur][r*32 + p*8]);
        }
        #pragma unroll
        for (int i = 0; i < FN; ++i) {
            int r = wc * (TN/2) + i*16 + l15;
            int p = g ^ ((r >> 1) & 3);
            bfr[i] = *reinterpret_cast<const bf16x8*>(&Bs[cur][r*32 + p*8]);
        }
        #pragma unroll
        for (int i = 0; i < FM; ++i)
            #pragma unroll
            for (int jj = 0; jj < FN; ++jj)
                acc[i][jj] = __builtin_amdgcn_mfma_f32_16x16x32_bf16(bfr[jj], af[i], acc[i][jj], 0, 0, 0);

        cur  = (cur  == 2) ? 0 : cur + 1;
        sbuf = (sbuf == 2) ? 0 : sbuf + 1;
    }

    #pragma unroll
    for (int i = 0; i < FM; ++i) {
        int m = row0 + wr * (TM/2) + i*16 + l15;
        #pragma unroll
        for (int jj = 0; jj < FN; ++jj) {
            int n0 = col0 + wc * (TN/2) + jj*16 + g*4;
            if (n0 < N) {
                f32x4 v = acc[i][jj];
                if (EPI == 2) {
                    float4* p = reinterpret_cast<float4*>(&C[(size_t)m * ldc + n0]);
                    float4 o = *p;
                    o.x += v[0]; o.y += v[1]; o.z += v[2]; o.w += v[3];
                    *p = o;
                } else if (EPI == 4) {
                    ushort4 o;
                    o.x = f2b(v[0]); o.y = f2b(v[1]); o.z = f2b(v[2]); o.w = f2b(v[3]);
                    *reinterpret_cast<ushort4*>(&Cb[(size_t)m * ldc + n0]) = o;
                } else if (EPI == 5) {
                    if (n0 < 768) {
                        float4 bv = *reinterpret_cast<const float4*>(&bias[n0]);
                        ushort4 o;
                        o.x = f2b(softplus_f(v[0] + bv.x));
                        o.y = f2b(softplus_f(v[1] + bv.y));
                        o.z = f2b(softplus_f(v[2] + bv.z));
                        o.w = f2b(softplus_f(v[3] + bv.w));
                        *reinterpret_cast<ushort4*>(&Cb[(size_t)m * ldc + n0]) = o;  // dt bf16, ldc=768
                    } else {
                        float4 o; o.x = v[0]; o.y = v[1]; o.z = v[2]; o.w = v[3];
                        *reinterpret_cast<float4*>(&C[(size_t)m * 32 + (n0 - 768)]) = o;  // bc f32
                    }
                } else {
                    float4 o; o.x = v[0]; o.y = v[1]; o.z = v[2]; o.w = v[3];
                    *reinterpret_cast<float4*>(&C[(size_t)m * ldc + n0]) = o;
                }
            }
        }
    }
}

// ---------------------------------------------------------------- fused chunked scan
// One cooperative kernel = old p1 -> grid.sync -> p2 -> grid.sync -> p3.
// Grid (3, NCHUNK, BATCH) = 768 blocks x 256 thr; block <-> (b, chunk, e-slice).
// h_end/decay/h_init layout: [b][e][n][c] (c innermost, NCHUNK=64), bf16.
// bc layout: [row][32] (B: 0..15, C: 16..31), f32.  dt is bf16.
// LDS BCs tile staged ONCE (phase 1) and reused in phase 3; a[16] kept in regs.
__global__ __launch_bounds__(256)
void scan_fused(const ushort* __restrict__ dtb, const ushort* __restrict__ xin_b,
                const ushort* __restrict__ xz_b, const float* __restrict__ bc,
                const float* __restrict__ A_log, const float* __restrict__ Dp,
                ushort* __restrict__ h_end, ushort* __restrict__ decay,
                ushort* __restrict__ h_init, ushort* __restrict__ y)
{
    __shared__ float BCs[CLEN][32];                 // 4 KB (B:0..15, C:16..31)
    int b = blockIdx.z, c = blockIdx.y;
    int e = blockIdx.x * 256 + threadIdx.x;
    size_t r0 = (size_t)b * SEQ + (size_t)c * CLEN;

    // stage full B+C tile once (phase 1 uses B cols, phase 3 uses both)
    for (int i = threadIdx.x; i < CLEN*32; i += 256) {
        int l = i >> 5, r = i & 31;
        BCs[l][r] = bc[(r0 + l) * 32 + r];
    }
    __syncthreads();

    float a[16];
    const float4* ap = reinterpret_cast<const float4*>(A_log + e * D_STATE);
    #pragma unroll
    for (int q = 0; q < 4; ++q) {
        float4 av = ap[q];
        a[q*4+0] = -__expf(av.x); a[q*4+1] = -__expf(av.y);
        a[q*4+2] = -__expf(av.z); a[q*4+3] = -__expf(av.w);
    }

    const ushort* pdt = dtb   + r0 * D_INNER + e;
    const ushort* px  = xin_b + r0 * D_INNER + e;

    // ---- phase 1: local scan from h=0 -> h_end, decay ----
    {
        float h[16];
        #pragma unroll
        for (int n = 0; n < 16; ++n) h[n] = 0.f;
        float S = 0.f;
        float dtv = b2f(pdt[0]), xv = b2f(px[0]);
        for (int l = 0; l < CLEN; ++l) {
            float dtn = 0.f, xn2 = 0.f;
            if (l + 1 < CLEN) {
                dtn = b2f(pdt[(size_t)(l+1) * D_INNER]);
                xn2 = b2f(px [(size_t)(l+1) * D_INNER]);
            }
            float dtx = dtv * xv;
            S += dtv;
            const float4* br = reinterpret_cast<const float4*>(&BCs[l][0]);
            float4 B0 = br[0], B1 = br[1], B2 = br[2], B3 = br[3];
            float Bv[16] = {B0.x,B0.y,B0.z,B0.w, B1.x,B1.y,B1.z,B1.w,
                            B2.x,B2.y,B2.z,B2.w, B3.x,B3.y,B3.z,B3.w};
            #pragma unroll
            for (int n = 0; n < 16; ++n) {
                float ex = __expf(dtv * a[n]);
                h[n] = h[n] * ex + dtx * Bv[n];
            }
            dtv = dtn; xv = xn2;
        }
        size_t base = (((size_t)b * D_INNER + e) * D_STATE) * NCHUNK + c;
        #pragma unroll
        for (int n = 0; n < 16; ++n) {
            h_end[base + (size_t)n * NCHUNK] = f2b(h[n]);
            decay[base + (size_t)n * NCHUNK] = f2b(__expf(a[n] * S));
        }
    }

    cg::this_grid().sync();

    // ---- phase 2: Hillis-Steele chunk combine, 16 tasks per wave ----
    {
        int flatb = blockIdx.x + gridDim.x * (blockIdx.y + gridDim.y * blockIdx.z);
        int gw    = flatb * 4 + (threadIdx.x >> 6);     // 3072 waves
        int lane  = threadIdx.x & 63;
        #pragma unroll 4
        for (int t = 0; t < 16; ++t) {
            size_t base = ((size_t)gw * 16 + t) * NCHUNK;
            float d = b2f(decay[base + lane]);
            float v = b2f(h_end[base + lane]);
            #pragma unroll
            for (int off = 1; off < 64; off <<= 1) {
                float dp = __shfl_up(d, off, 64);
                float vp = __shfl_up(v, off, 64);
                if (lane >= off) { v = fmaf(d, vp, v); d *= dp; }
            }
            float hi = __shfl_up(v, 1, 64);
            if (lane == 0) hi = 0.f;
            h_init[base + lane] = f2b(hi);
        }
    }

    cg::this_grid().sync();

    // ---- phase 3: re-scan from h_init; y + D-skip + gate -> bf16 ----
    {
        float dskip = Dp[e];
        float h[16];
        size_t hbase = (((size_t)b * D_INNER + e) * D_STATE) * NCHUNK + c;
        #pragma unroll
        for (int n = 0; n < 16; ++n) h[n] = b2f(h_init[hbase + (size_t)n * NCHUNK]);

        const ushort* pz = xz_b + r0 * (2*D_INNER) + D_INNER + e;
        ushort*       py = y    + r0 * D_INNER + e;

        float dtv = b2f(pdt[0]), xv = b2f(px[0]), zv = b2f(pz[0]);
        for (int l = 0; l < CLEN; ++l) {
            float dtn = 0.f, xn2 = 0.f, zn = 0.f;
            if (l + 1 < CLEN) {
                dtn = b2f(pdt[(size_t)(l+1) * D_INNER]);
                xn2 = b2f(px [(size_t)(l+1) * D_INNER]);
                zn  = b2f(pz [(size_t)(l+1) * (2*D_INNER)]);
            }
            float dtx = dtv * xv;
            const float4* br = reinterpret_cast<const float4*>(&BCs[l][0]);
            float4 B0 = br[0], B1 = br[1], B2 = br[2], B3 = br[3];
            float Bv[16] = {B0.x,B0.y,B0.z,B0.w, B1.x,B1.y,B1.z,B1.w,
                            B2.x,B2.y,B2.z,B2.w, B3.x,B3.y,B3.z,B3.w};
            #pragma unroll
            for (int n = 0; n < 16; ++n) {
                float ex = __expf(dtv * a[n]);
                h[n] = h[n] * ex + dtx * Bv[n];
            }
            float4 C0 = br[4], C1 = br[5], C2 = br[6], C3 = br[7];
            float Cv[16] = {C0.x,C0.y,C0.z,C0.w, C1.x,C1.y,C1.z,C1.w,
                            C2.x,C2.y,C2.z,C2.w, C3.x,C3.y,C3.z,C3.w};
            float yv = 0.f;
            #pragma unroll
            for (int n = 0; n < 16; ++n) yv += h[n] * Cv[n];

            float g = zv / (1.f + __expf(-zv));     // silu(z)
            py[(size_t)l * D_INNER] = f2b((yv + xv * dskip) * g);

            dtv = dtn; xv = xn2; zv = zn;
        }
    }
}

// ---------------------------------------------------------------- launch
extern "C" void kernel_launch(void* const* d_in, const int* in_sizes, int n_in,
                              void* d_out, int out_size, void* d_ws, size_t ws_size,
                              hipStream_t stream)
{
    const int*   tokens       = (const int*)  d_in[0];
    const float* embed        = (const float*)d_in[1];
    const float* norm_w       = (const float*)d_in[2];
    const float* in_proj_w    = (const float*)d_in[3];
    const float* conv_w       = (const float*)d_in[4];
    const float* conv_b       = (const float*)d_in[5];
    const float* x_proj_w     = (const float*)d_in[6];
    const float* dt_proj_w    = (const float*)d_in[7];
    const float* dt_proj_b    = (const float*)d_in[8];
    const float* A_log        = (const float*)d_in[9];
    const float* D_param      = (const float*)d_in[10];
    const float* out_proj_w   = (const float*)d_in[11];
    const float* final_norm_w = (const float*)d_in[12];
    float* out = (float*)d_out;

    // ---- workspace map (float offsets), ~36 MB
    float* ws = (float*)d_ws;
    float*  x      = ws;                          // 3,145,728 f
    ushort* inw_b  = (ushort*)(ws + 3145728);     // 2,359,296 us -> f 4,325,376
    ushort* outw_b = (ushort*)(ws + 4325376);     // 1,179,648 us -> 4,915,200
    ushort* emb_b  = (ushort*)(ws + 4915200);     // 5120*384 us  -> 5,898,240 (rows>=5000 junk, never stored)
    ushort* wf_b   = (ushort*)(ws + 5898240);     // 4*896*768 us -> 7,274,496
    float*  bc     = ws + 7274496;                // 262,144 f    -> 7,536,640
    ushort* xn_b   = (ushort*)(ws + 7536640);     // 3,145,728 us -> 9,109,504

    // ---- big scratch in d_out (40,960,000 floats; all dead before lm_head)
    ushort* xz_b   = (ushort*)out;                // 12,582,912 us -> f 6,291,456
    ushort* dtb    = (ushort*)(out + 6291456);    // 6,291,456 us -> 9,437,184
    ushort* y_b    = (ushort*)(out + 9437184);    // -> 12,582,912
    ushort* xin_b  = (ushort*)(out + 12582912);   // -> 15,728,640
    ushort* h_end  = (ushort*)(out + 15728640);   // 3,145,728 us -> 17,301,504
    ushort* decay  = (ushort*)(out + 17301504);   // -> 18,874,368
    ushort* h_init = (ushort*)(out + 18874368);   // -> 20,447,232 (< 40,960,000)

    dim3 blk(256);

    // fused one-shot prep (5 jobs in one node); 4,903,680 flat jobs
    prep_k<<<19155, blk, 0, stream>>>(in_proj_w, out_proj_w, embed, x_proj_w,
                                      dt_proj_w, tokens,
                                      inw_b, outw_b, emb_b, wf_b, x);

    for (int i = 0; i < N_LAYER; ++i) {
        rmsnorm_k<<<ROWS/4, blk, 0, stream>>>(x, norm_w + i*D_MODEL, xn_b);
        // in_proj: 8192 x 1536 x 384 -> bf16 xz
        gemm_lds<128,128,4><<<dim3(12, 64), blk, 0, stream>>>(
            xn_b, D_MODEL, inw_b + (size_t)i*2*D_INNER*D_MODEL, D_MODEL,
            nullptr, 2*D_INNER, xz_b, nullptr, 2*D_INNER, D_MODEL);
        // conv + silu -> xin bf16
        conv_silu_k<<<ROWS*192/256, blk, 0, stream>>>(
            xz_b, conv_w + i*D_INNER*D_CONV, conv_b + i*D_INNER, xin_b);
        // fused x_proj+dt_proj: 8192 x 800(pad 832) x 768
        //   n<768: dt = softplus(.+bias) -> dtb (bf16) ; n in [768,800) -> bc (f32)
        gemm_lds<128,64,5><<<dim3(13, 64), blk, 0, stream>>>(
            xin_b, D_INNER, wf_b + (size_t)i*896*D_INNER, D_INNER,
            bc, D_INNER, dtb, dt_proj_b + i*D_INNER, 800, D_INNER);
        // fused chunked selective scan (cooperative: p1 -> p2 -> p3)
        {
            const ushort* dtb_c  = dtb;
            const ushort* xin_c  = xin_b;
            const ushort* xz_c   = xz_b;
            const float*  bc_c   = bc;
            const float*  Al_c   = A_log + (size_t)i*D_INNER*D_STATE;
            const float*  Dp_c   = D_param + (size_t)i*D_INNER;
            ushort* he_c = h_end; ushort* de_c = decay; ushort* hi_c = h_init;
            ushort* y_c  = y_b;
            void* args[] = { (void*)&dtb_c, (void*)&xin_c, (void*)&xz_c, (void*)&bc_c,
                             (void*)&Al_c, (void*)&Dp_c, (void*)&he_c, (void*)&de_c,
                             (void*)&hi_c, (void*)&y_c };
            hipLaunchCooperativeKernel((const void*)scan_fused,
                                       dim3(3, NCHUNK, BATCH), blk, args, 0, stream);
        }
        // out_proj + residual: 8192 x 384 x 768, x += ... (float4 RMW)
        gemm_lds<64,64,2><<<dim3(6, 128), blk, 0, stream>>>(
            y_b, D_INNER, outw_b + (size_t)i*D_MODEL*D_INNER, D_INNER,
            x, D_MODEL, nullptr, nullptr, D_MODEL, D_INNER);
    }

    rmsnorm_k<<<ROWS/4, blk, 0, stream>>>(x, final_norm_w, xn_b);
    // lm_head: 8192 x 5000 x 384 (overwrites ALL of d_out; float4 stores)
    gemm_lds<128,128,0><<<dim3(40, 64), blk, 0, stream>>>(
        xn_b, D_MODEL, emb_b, D_MODEL, out, VOCAB, nullptr, nullptr, VOCAB, D_MODEL);
}

// Round 16
// 952.379 us; speedup vs baseline: 1.8769x; 1.8769x over previous
//
#include <hip/hip_runtime.h>
#include <hip/hip_bf16.h>

#define D_MODEL 384
#define N_LAYER 4
#define VOCAB   5000
#define D_INNER 768
#define D_STATE 16
#define DT_RANK 24
#define D_CONV  4
#define BATCH   4
#define SEQ     2048
#define ROWS    (BATCH*SEQ)          // 8192
#define NCHUNK  64
#define CLEN    32                   // NCHUNK*CLEN == SEQ

typedef __attribute__((ext_vector_type(8))) short bf16x8;
typedef __attribute__((ext_vector_type(4))) float f32x4;

// fp32 -> bf16 (RNE), finite inputs only
static __device__ __forceinline__ ushort f2b(float f) {
    uint u = __float_as_uint(f);
    return (ushort)((u + 0x7FFFu + ((u >> 16) & 1u)) >> 16);
}
static __device__ __forceinline__ float b2f(ushort u) {
    return __uint_as_float((uint)u << 16);
}
// branchless softplus, hardware exp/log only (no libm call)
static __device__ __forceinline__ float softplus_f(float v) {
    return fmaxf(v, 0.f) + __logf(1.f + __expf(-fabsf(v)));
}

// async global->LDS, 16B per lane (dst = wave base + lane*16, linear)
static __device__ __forceinline__ void gl_lds16(const void* g, void* l) {
    __builtin_amdgcn_global_load_lds(
        (const __attribute__((address_space(1))) void*)g,
        (__attribute__((address_space(3))) void*)l, 16, 0, 0);
}

// s_waitcnt with vmcnt=N, lgkmcnt/expcnt = don't-care
template<int N> static __device__ __forceinline__ void waitcnt_vm() {
    __builtin_amdgcn_s_waitcnt((N & 0xF) | (7 << 4) | (0xF << 8) | (((N >> 4) & 3) << 14));
}

// ---------------------------------------------------------------- fused one-shot prep
// Jobs (flat index space):
//   [0, 589824)            : in_proj_w  f32x4 -> bf16x4
//   [589824, 884736)       : out_proj_w f32x4 -> bf16x4
//   [884736, 1364736)      : embed      f32x4 -> bf16x4
//   [1364736, 4117248)     : wf element (build fused proj weight)
//   [4117248, 4903680)     : embed gather -> x (float4 per job)
__global__ __launch_bounds__(256)
void prep_k(const float* __restrict__ inw, const float* __restrict__ outw,
            const float* __restrict__ emb, const float* __restrict__ xpw,
            const float* __restrict__ dtw, const int* __restrict__ tokens,
            ushort* __restrict__ inw_b, ushort* __restrict__ outw_b,
            ushort* __restrict__ emb_b, ushort* __restrict__ wf,
            float* __restrict__ x)
{
    int idx = blockIdx.x * 256 + threadIdx.x;
    if (idx < 589824) {
        float4 v = reinterpret_cast<const float4*>(inw)[idx];
        ushort4 o; o.x=f2b(v.x); o.y=f2b(v.y); o.z=f2b(v.z); o.w=f2b(v.w);
        reinterpret_cast<ushort4*>(inw_b)[idx] = o;
    } else if (idx < 884736) {
        int i = idx - 589824;
        float4 v = reinterpret_cast<const float4*>(outw)[i];
        ushort4 o; o.x=f2b(v.x); o.y=f2b(v.y); o.z=f2b(v.z); o.w=f2b(v.w);
        reinterpret_cast<ushort4*>(outw_b)[i] = o;
    } else if (idx < 1364736) {
        int i = idx - 884736;
        float4 v = reinterpret_cast<const float4*>(emb)[i];
        ushort4 o; o.x=f2b(v.x); o.y=f2b(v.y); o.z=f2b(v.z); o.w=f2b(v.w);
        reinterpret_cast<ushort4*>(emb_b)[i] = o;
    } else if (idx < 4117248) {
        int i = idx - 1364736;                      // 4*896*768 elements
        int l = i / (896*768); int rk = i % (896*768);
        int r = rk / 768, k = rk % 768;
        float v = 0.f;
        if (r < 768) {
            const float* dr = dtw + ((size_t)l*768 + r)*24;
            const float* xc = xpw + (size_t)l*56*768 + k;
            #pragma unroll
            for (int q = 0; q < 24; ++q) v += dr[q] * xc[(size_t)q*768];
        } else if (r < 800) {
            v = xpw[((size_t)l*56 + 24 + (r-768))*768 + k];
        }
        wf[i] = f2b(v);
    } else {
        int i = idx - 4117248;                      // ROWS*96 float4 jobs
        int row = i / 96, c4 = i % 96;
        int tok = tokens[row];
        reinterpret_cast<float4*>(x)[(size_t)row * 96 + c4] =
            reinterpret_cast<const float4*>(emb)[(size_t)tok * 96 + c4];
    }
}

// ---------------------------------------------------------------- rmsnorm -> bf16
__global__ __launch_bounds__(256)
void rmsnorm_k(const float* __restrict__ xin, const float* __restrict__ w,
               ushort* __restrict__ xout)
{
    int row  = blockIdx.x * 4 + (threadIdx.x >> 6);
    int lane = threadIdx.x & 63;
    const float* xr = xin + (size_t)row * D_MODEL;
    float v[6]; float ss = 0.f;
    #pragma unroll
    for (int j = 0; j < 6; ++j) { v[j] = xr[lane + 64*j]; ss += v[j]*v[j]; }
    #pragma unroll
    for (int m = 32; m; m >>= 1) ss += __shfl_xor(ss, m, 64);
    float r = rsqrtf(ss * (1.f/D_MODEL) + 1e-5f);
    ushort* yo = xout + (size_t)row * D_MODEL;
    #pragma unroll
    for (int j = 0; j < 6; ++j) yo[lane + 64*j] = f2b(v[j] * w[lane + 64*j] * r);
}

// ---------------------------------------------------------------- conv1d + silu -> bf16
// 4 channels per thread: ushort4 loads/stores, float4 weights.
__global__ __launch_bounds__(256)
void conv_silu_k(const ushort* __restrict__ xz_b, const float* __restrict__ cw,
                 const float* __restrict__ cb, ushort* __restrict__ xout_b)
{
    int idx = blockIdx.x * 256 + threadIdx.x;       // ROWS * 192
    int e4  = idx % 192;                            // quad of channels
    int row = idx / 192;
    int e   = e4 * 4;
    int l   = row & (SEQ - 1);

    float4 w0 = reinterpret_cast<const float4*>(cw)[e4*4 + 0];
    float4 w1 = reinterpret_cast<const float4*>(cw)[e4*4 + 1];
    float4 w2 = reinterpret_cast<const float4*>(cw)[e4*4 + 2];
    float4 w3 = reinterpret_cast<const float4*>(cw)[e4*4 + 3];
    float4 bv = reinterpret_cast<const float4*>(cb)[e4];
    float ac0 = bv.x, ac1 = bv.y, ac2 = bv.z, ac3 = bv.w;

    #pragma unroll
    for (int j = 0; j < 4; ++j) {
        if (l - j >= 0) {
            ushort4 v = *reinterpret_cast<const ushort4*>(
                &xz_b[(size_t)(row - j) * (2*D_INNER) + e]);
            float wj0 = (&w0.x)[3-j], wj1 = (&w1.x)[3-j],
                  wj2 = (&w2.x)[3-j], wj3 = (&w3.x)[3-j];
            ac0 += wj0 * b2f(v.x); ac1 += wj1 * b2f(v.y);
            ac2 += wj2 * b2f(v.z); ac3 += wj3 * b2f(v.w);
        }
    }
    ushort4 o;
    o.x = f2b(ac0 / (1.f + __expf(-ac0)));
    o.y = f2b(ac1 / (1.f + __expf(-ac1)));
    o.z = f2b(ac2 / (1.f + __expf(-ac2)));
    o.w = f2b(ac3 / (1.f + __expf(-ac3)));
    *reinterpret_cast<ushort4*>(&xout_b[(size_t)row * D_INNER + e]) = o;
}

// ---------------------------------------------------------------- LDS-staged MFMA GEMM
// C[M,N](f32) = A[M,K](bf16) @ B[N,K](bf16)^T.
// 3-buf counted-vmcnt pipeline; swapped-operand MFMA (lane holds C row m = l15,
// 4 consecutive cols); XOR-swizzled LDS (both-sides).
// EPI: 0 store f32x4 (C) | 2 C += (f32x4 RMW) | 4 store bf16x4 (Cb, ldc)
//      5 fused-proj: n<768 -> softplus(v+bias[n]) -> bf16x4 Cb (ldc=768) ;
//                    768<=n<800 -> f32x4 -> C[m*32 + n-768]  (bc buffer)
template<int TM, int TN, int EPI>
__global__ __launch_bounds__(256)
void gemm_lds(const ushort* __restrict__ A, int lda,
              const ushort* __restrict__ B, int ldb,
              float* __restrict__ C, int ldc,
              ushort* __restrict__ Cb, const float* __restrict__ bias,
              int N, int K)
{
    constexpr int FM = TM / 32, FN = TN / 32;
    constexpr int LPT = TM/64 + TN/64;
    __shared__ alignas(16) ushort As[3][TM * 32];
    __shared__ alignas(16) ushort Bs[3][TN * 32];
    int tid = threadIdx.x, w = tid >> 6, l = tid & 63;
    int wr = w >> 1, wc = w & 1;
    int row0 = blockIdx.y * TM, col0 = blockIdx.x * TN;
    int l15 = l & 15, g = l >> 4;
    int sr = l >> 2, sp = l & 3;

    f32x4 acc[FM][FN] = {};

    auto stage = [&](int buf, int k0) {
        #pragma unroll
        for (int j = 0; j < TM/64; ++j) {
            int ai = w * (TM/64) + j;
            int r  = ai * 16 + sr;
            int s  = sp ^ ((r >> 1) & 3);
            gl_lds16(&A[(size_t)(row0 + r) * lda + k0 + s*8], &As[buf][ai * 512]);
        }
        #pragma unroll
        for (int j = 0; j < TN/64; ++j) {
            int bi = w * (TN/64) + j;
            int r  = bi * 16 + sr;
            int s  = sp ^ ((r >> 1) & 3);
            gl_lds16(&B[(size_t)(col0 + r) * ldb + k0 + s*8], &Bs[buf][bi * 512]);
        }
    };

    int nk = K >> 5;
    stage(0, 0);
    if (nk > 1) stage(1, 32);

    int cur = 0, sbuf = 2;
    for (int t = 0; t < nk; ++t) {
        if (t < nk - 1) waitcnt_vm<LPT>();
        else            waitcnt_vm<0>();
        __builtin_amdgcn_sched_barrier(0);
        __builtin_amdgcn_s_barrier();
        __builtin_amdgcn_sched_barrier(0);
        if (t + 2 < nk) stage(sbuf, (t + 2) << 5);
        __builtin_amdgcn_sched_barrier(0);

        bf16x8 af[FM], bfr[FN];
        #pragma unroll
        for (int i = 0; i < FM; ++i) {
            int r = wr * (TM/2) + i*16 + l15;
            int p = g ^ ((r >> 1) & 3);
            af[i] = *reinterpret_cast<const bf16x8*>(&As[cur][r*32 + p*8]);
        }
        #pragma unroll
        for (int i = 0; i < FN; ++i) {
            int r = wc * (TN/2) + i*16 + l15;
            int p = g ^ ((r >> 1) & 3);
            bfr[i] = *reinterpret_cast<const bf16x8*>(&Bs[cur][r*32 + p*8]);
        }
        #pragma unroll
        for (int i = 0; i < FM; ++i)
            #pragma unroll
            for (int jj = 0; jj < FN; ++jj)
                acc[i][jj] = __builtin_amdgcn_mfma_f32_16x16x32_bf16(bfr[jj], af[i], acc[i][jj], 0, 0, 0);

        cur  = (cur  == 2) ? 0 : cur + 1;
        sbuf = (sbuf == 2) ? 0 : sbuf + 1;
    }

    #pragma unroll
    for (int i = 0; i < FM; ++i) {
        int m = row0 + wr * (TM/2) + i*16 + l15;
        #pragma unroll
        for (int jj = 0; jj < FN; ++jj) {
            int n0 = col0 + wc * (TN/2) + jj*16 + g*4;
            if (n0 < N) {
                f32x4 v = acc[i][jj];
                if (EPI == 2) {
                    float4* p = reinterpret_cast<float4*>(&C[(size_t)m * ldc + n0]);
                    float4 o = *p;
                    o.x += v[0]; o.y += v[1]; o.z += v[2]; o.w += v[3];
                    *p = o;
                } else if (EPI == 4) {
                    ushort4 o;
                    o.x = f2b(v[0]); o.y = f2b(v[1]); o.z = f2b(v[2]); o.w = f2b(v[3]);
                    *reinterpret_cast<ushort4*>(&Cb[(size_t)m * ldc + n0]) = o;
                } else if (EPI == 5) {
                    if (n0 < 768) {
                        float4 bv = *reinterpret_cast<const float4*>(&bias[n0]);
                        ushort4 o;
                        o.x = f2b(softplus_f(v[0] + bv.x));
                        o.y = f2b(softplus_f(v[1] + bv.y));
                        o.z = f2b(softplus_f(v[2] + bv.z));
                        o.w = f2b(softplus_f(v[3] + bv.w));
                        *reinterpret_cast<ushort4*>(&Cb[(size_t)m * ldc + n0]) = o;  // dt bf16, ldc=768
                    } else {
                        float4 o; o.x = v[0]; o.y = v[1]; o.z = v[2]; o.w = v[3];
                        *reinterpret_cast<float4*>(&C[(size_t)m * 32 + (n0 - 768)]) = o;  // bc f32
                    }
                } else {
                    float4 o; o.x = v[0]; o.y = v[1]; o.z = v[2]; o.w = v[3];
                    *reinterpret_cast<float4*>(&C[(size_t)m * ldc + n0]) = o;
                }
            }
        }
    }
}

// ---------------------------------------------------------------- chunked scan
// Thread <-> (b, chunk, e); all 16 states in registers.
// h_end/decay layout: [b][e][c][n]  (n innermost, 16 contiguous bf16 per chunk).
// bc layout: [row][32]  (B: 0..15, C: 16..31), f32.  dt is bf16.  NO p2 pass:
// p3 computes its own entering-state prefix (c is block-uniform -> no divergence).

__global__ __launch_bounds__(256)
void scan_p1(const ushort* __restrict__ dtb, const ushort* __restrict__ xin_b,
             const float* __restrict__ bc, const float* __restrict__ A_log,
             ushort* __restrict__ h_end, ushort* __restrict__ decay)
{
    __shared__ float Bs[CLEN][16];
    int b = blockIdx.z, c = blockIdx.y;
    int e = blockIdx.x * 256 + threadIdx.x;
    size_t r0 = (size_t)b * SEQ + (size_t)c * CLEN;

    for (int i = threadIdx.x; i < CLEN*16; i += 256) {
        int l = i >> 4, n = i & 15;
        Bs[l][n] = bc[(r0 + l) * 32 + n];
    }
    __syncthreads();

    float a[16];
    const float4* ap = reinterpret_cast<const float4*>(A_log + e * D_STATE);
    #pragma unroll
    for (int q = 0; q < 4; ++q) {
        float4 av = ap[q];
        a[q*4+0] = -__expf(av.x); a[q*4+1] = -__expf(av.y);
        a[q*4+2] = -__expf(av.z); a[q*4+3] = -__expf(av.w);
    }

    const ushort* pdt = dtb   + r0 * D_INNER + e;
    const ushort* px  = xin_b + r0 * D_INNER + e;
    float h[16];
    #pragma unroll
    for (int n = 0; n < 16; ++n) h[n] = 0.f;
    float S = 0.f;
    float dtv = b2f(pdt[0]), xv = b2f(px[0]);

    for (int l = 0; l < CLEN; ++l) {
        float dtn = 0.f, xn2 = 0.f;
        if (l + 1 < CLEN) {
            dtn = b2f(pdt[(size_t)(l+1) * D_INNER]);
            xn2 = b2f(px [(size_t)(l+1) * D_INNER]);
        }
        float dtx = dtv * xv;
        S += dtv;
        const float4* br = reinterpret_cast<const float4*>(&Bs[l][0]);
        float4 B0 = br[0], B1 = br[1], B2 = br[2], B3 = br[3];
        float Bv[16] = {B0.x,B0.y,B0.z,B0.w, B1.x,B1.y,B1.z,B1.w,
                        B2.x,B2.y,B2.z,B2.w, B3.x,B3.y,B3.z,B3.w};
        #pragma unroll
        for (int n = 0; n < 16; ++n) {
            float ex = __expf(dtv * a[n]);
            h[n] = h[n] * ex + dtx * Bv[n];
        }
        dtv = dtn; xv = xn2;
    }

    // [b][e][c][n] layout: 16 contiguous bf16 per (chunk)
    size_t base = ((((size_t)b * D_INNER + e) * NCHUNK) + c) * 16;
    bf16x8 hv0, hv1, dv0, dv1;
    float dcy[16];
    #pragma unroll
    for (int n = 0; n < 16; ++n) dcy[n] = __expf(a[n] * S);
    #pragma unroll
    for (int n = 0; n < 8; ++n) {
        hv0[n] = (short)f2b(h[n]);     hv1[n] = (short)f2b(h[8+n]);
        dv0[n] = (short)f2b(dcy[n]);   dv1[n] = (short)f2b(dcy[8+n]);
    }
    *reinterpret_cast<bf16x8*>(&h_end[base])     = hv0;
    *reinterpret_cast<bf16x8*>(&h_end[base + 8]) = hv1;
    *reinterpret_cast<bf16x8*>(&decay[base])     = dv0;
    *reinterpret_cast<bf16x8*>(&decay[base + 8]) = dv1;
}

// Pass 3: compute own entering-state prefix, then re-scan chunk; y -> bf16
__global__ __launch_bounds__(256)
void scan_p3(const ushort* __restrict__ dtb, const ushort* __restrict__ xin_b,
             const ushort* __restrict__ xz_b, const float* __restrict__ bc,
             const float* __restrict__ A_log, const float* __restrict__ Dp,
             const ushort* __restrict__ h_end, const ushort* __restrict__ decay,
             ushort* __restrict__ y)
{
    __shared__ float BCs[CLEN][32];
    int b = blockIdx.z, c = blockIdx.y;
    int e = blockIdx.x * 256 + threadIdx.x;
    size_t r0 = (size_t)b * SEQ + (size_t)c * CLEN;

    for (int i = threadIdx.x; i < CLEN*32; i += 256) {
        int l = i >> 5, r = i & 31;
        BCs[l][r] = bc[(r0 + l) * 32 + r];
    }

    // prefix: H = state entering chunk c (forward recurrence over c' < c).
    float h[16];
    #pragma unroll
    for (int n = 0; n < 16; ++n) h[n] = 0.f;
    {
        size_t sbase = (((size_t)b * D_INNER + e) * NCHUNK) * 16;
        const ushort* he = h_end + sbase;
        const ushort* de = decay + sbase;
        for (int cc = 0; cc < c; ++cc) {
            bf16x8 hv0 = *reinterpret_cast<const bf16x8*>(he + cc*16);
            bf16x8 hv1 = *reinterpret_cast<const bf16x8*>(he + cc*16 + 8);
            bf16x8 dv0 = *reinterpret_cast<const bf16x8*>(de + cc*16);
            bf16x8 dv1 = *reinterpret_cast<const bf16x8*>(de + cc*16 + 8);
            #pragma unroll
            for (int n = 0; n < 8; ++n) {
                h[n]   = fmaf(b2f((ushort)dv0[n]), h[n],   b2f((ushort)hv0[n]));
                h[8+n] = fmaf(b2f((ushort)dv1[n]), h[8+n], b2f((ushort)hv1[n]));
            }
        }
    }
    __syncthreads();

    float a[16];
    const float4* ap = reinterpret_cast<const float4*>(A_log + e * D_STATE);
    #pragma unroll
    for (int q = 0; q < 4; ++q) {
        float4 av = ap[q];
        a[q*4+0] = -__expf(av.x); a[q*4+1] = -__expf(av.y);
        a[q*4+2] = -__expf(av.z); a[q*4+3] = -__expf(av.w);
    }
    float dskip = Dp[e];

    const ushort* pdt = dtb   + r0 * D_INNER + e;
    const ushort* px  = xin_b + r0 * D_INNER + e;
    const ushort* pz  = xz_b  + r0 * (2*D_INNER) + D_INNER + e;
    ushort*       py  = y     + r0 * D_INNER + e;

    float dtv = b2f(pdt[0]), xv = b2f(px[0]), zv = b2f(pz[0]);

    for (int l = 0; l < CLEN; ++l) {
        float dtn = 0.f, xn2 = 0.f, zn = 0.f;
        if (l + 1 < CLEN) {
            dtn = b2f(pdt[(size_t)(l+1) * D_INNER]);
            xn2 = b2f(px [(size_t)(l+1) * D_INNER]);
            zn  = b2f(pz [(size_t)(l+1) * (2*D_INNER)]);
        }
        float dtx = dtv * xv;
        const float4* br = reinterpret_cast<const float4*>(&BCs[l][0]);
        float4 B0 = br[0], B1 = br[1], B2 = br[2], B3 = br[3];
        float Bv[16] = {B0.x,B0.y,B0.z,B0.w, B1.x,B1.y,B1.z,B1.w,
                        B2.x,B2.y,B2.z,B2.w, B3.x,B3.y,B3.z,B3.w};
        #pragma unroll
        for (int n = 0; n < 16; ++n) {
            float ex = __expf(dtv * a[n]);
            h[n] = h[n] * ex + dtx * Bv[n];
        }
        float4 C0 = br[4], C1 = br[5], C2 = br[6], C3 = br[7];
        float Cv[16] = {C0.x,C0.y,C0.z,C0.w, C1.x,C1.y,C1.z,C1.w,
                        C2.x,C2.y,C2.z,C2.w, C3.x,C3.y,C3.z,C3.w};
        float yv = 0.f;
        #pragma unroll
        for (int n = 0; n < 16; ++n) yv += h[n] * Cv[n];

        float g = zv / (1.f + __expf(-zv));         // silu(z)
        py[(size_t)l * D_INNER] = f2b((yv + xv * dskip) * g);

        dtv = dtn; xv = xn2; zv = zn;
    }
}

// ---------------------------------------------------------------- launch
extern "C" void kernel_launch(void* const* d_in, const int* in_sizes, int n_in,
                              void* d_out, int out_size, void* d_ws, size_t ws_size,
                              hipStream_t stream)
{
    const int*   tokens       = (const int*)  d_in[0];
    const float* embed        = (const float*)d_in[1];
    const float* norm_w       = (const float*)d_in[2];
    const float* in_proj_w    = (const float*)d_in[3];
    const float* conv_w       = (const float*)d_in[4];
    const float* conv_b       = (const float*)d_in[5];
    const float* x_proj_w     = (const float*)d_in[6];
    const float* dt_proj_w    = (const float*)d_in[7];
    const float* dt_proj_b    = (const float*)d_in[8];
    const float* A_log        = (const float*)d_in[9];
    const float* D_param      = (const float*)d_in[10];
    const float* out_proj_w   = (const float*)d_in[11];
    const float* final_norm_w = (const float*)d_in[12];
    float* out = (float*)d_out;

    // ---- workspace map (float offsets), ~36 MB
    float* ws = (float*)d_ws;
    float*  x      = ws;                          // 3,145,728 f
    ushort* inw_b  = (ushort*)(ws + 3145728);     // 2,359,296 us -> f 4,325,376
    ushort* outw_b = (ushort*)(ws + 4325376);     // 1,179,648 us -> 4,915,200
    ushort* emb_b  = (ushort*)(ws + 4915200);     // 5120*384 us  -> 5,898,240 (rows>=5000 junk, never stored)
    ushort* wf_b   = (ushort*)(ws + 5898240);     // 4*896*768 us -> 7,274,496
    float*  bc     = ws + 7274496;                // 262,144 f    -> 7,536,640
    ushort* xn_b   = (ushort*)(ws + 7536640);     // 3,145,728 us -> 9,109,504

    // ---- big scratch in d_out (40,960,000 floats; all dead before lm_head)
    ushort* xz_b   = (ushort*)out;                // 12,582,912 us -> f 6,291,456
    ushort* dtb    = (ushort*)(out + 6291456);    // 6,291,456 us -> 9,437,184
    ushort* y_b    = (ushort*)(out + 9437184);    // -> 12,582,912
    ushort* xin_b  = (ushort*)(out + 12582912);   // -> 15,728,640
    ushort* h_end  = (ushort*)(out + 15728640);   // 3,145,728 us -> 17,301,504
    ushort* decay  = (ushort*)(out + 17301504);   // -> 18,874,368 (< 40,960,000)

    dim3 blk(256);

    // fused one-shot prep (5 jobs in one node); 4,903,680 flat jobs
    prep_k<<<19155, blk, 0, stream>>>(in_proj_w, out_proj_w, embed, x_proj_w,
                                      dt_proj_w, tokens,
                                      inw_b, outw_b, emb_b, wf_b, x);

    for (int i = 0; i < N_LAYER; ++i) {
        rmsnorm_k<<<ROWS/4, blk, 0, stream>>>(x, norm_w + i*D_MODEL, xn_b);
        // in_proj: 8192 x 1536 x 384 -> bf16 xz
        gemm_lds<128,128,4><<<dim3(12, 64), blk, 0, stream>>>(
            xn_b, D_MODEL, inw_b + (size_t)i*2*D_INNER*D_MODEL, D_MODEL,
            nullptr, 2*D_INNER, xz_b, nullptr, 2*D_INNER, D_MODEL);
        // conv + silu -> xin bf16
        conv_silu_k<<<ROWS*192/256, blk, 0, stream>>>(
            xz_b, conv_w + i*D_INNER*D_CONV, conv_b + i*D_INNER, xin_b);
        // fused x_proj+dt_proj: 8192 x 800(pad 832) x 768
        //   n<768: dt = softplus(.+bias) -> dtb (bf16) ; n in [768,800) -> bc (f32)
        gemm_lds<128,64,5><<<dim3(13, 64), blk, 0, stream>>>(
            xin_b, D_INNER, wf_b + (size_t)i*896*D_INNER, D_INNER,
            bc, D_INNER, dtb, dt_proj_b + i*D_INNER, 800, D_INNER);
        // chunked selective scan: p1 then p3 (p3 computes its own prefix)
        scan_p1<<<dim3(3, NCHUNK, BATCH), blk, 0, stream>>>(
            dtb, xin_b, bc, A_log + (size_t)i*D_INNER*D_STATE, h_end, decay);
        scan_p3<<<dim3(3, NCHUNK, BATCH), blk, 0, stream>>>(
            dtb, xin_b, xz_b, bc, A_log + (size_t)i*D_INNER*D_STATE,
            D_param + i*D_INNER, h_end, decay, y_b);
        // out_proj + residual: 8192 x 384 x 768, x += ... (float4 RMW)
        gemm_lds<64,64,2><<<dim3(6, 128), blk, 0, stream>>>(
            y_b, D_INNER, outw_b + (size_t)i*D_MODEL*D_INNER, D_INNER,
            x, D_MODEL, nullptr, nullptr, D_MODEL, D_INNER);
    }

    rmsnorm_k<<<ROWS/4, blk, 0, stream>>>(x, final_norm_w, xn_b);
    // lm_head: 8192 x 5000 x 384 (overwrites ALL of d_out; float4 stores)
    gemm_lds<128,128,0><<<dim3(40, 64), blk, 0, stream>>>(
        xn_b, D_MODEL, emb_b, D_MODEL, out, VOCAB, nullptr, nullptr, VOCAB, D_MODEL);
}

// Round 17
// 863.433 us; speedup vs baseline: 2.0702x; 1.1030x over previous
//
#include <hip/hip_runtime.h>
#include <hip/hip_bf16.h>

#define D_MODEL 384
#define N_LAYER 4
#define VOCAB   5000
#define D_INNER 768
#define D_STATE 16
#define DT_RANK 24
#define D_CONV  4
#define BATCH   4
#define SEQ     2048
#define ROWS    (BATCH*SEQ)          // 8192
#define NCHUNK  64
#define CLEN    32                   // NCHUNK*CLEN == SEQ

typedef __attribute__((ext_vector_type(8))) short bf16x8;
typedef __attribute__((ext_vector_type(4))) float f32x4;

// fp32 -> bf16 (RNE), finite inputs only
static __device__ __forceinline__ ushort f2b(float f) {
    uint u = __float_as_uint(f);
    return (ushort)((u + 0x7FFFu + ((u >> 16) & 1u)) >> 16);
}
static __device__ __forceinline__ float b2f(ushort u) {
    return __uint_as_float((uint)u << 16);
}
// branchless softplus, hardware exp/log only (no libm call)
static __device__ __forceinline__ float softplus_f(float v) {
    return fmaxf(v, 0.f) + __logf(1.f + __expf(-fabsf(v)));
}

// async global->LDS, 16B per lane (dst = wave base + lane*16, linear)
static __device__ __forceinline__ void gl_lds16(const void* g, void* l) {
    __builtin_amdgcn_global_load_lds(
        (const __attribute__((address_space(1))) void*)g,
        (__attribute__((address_space(3))) void*)l, 16, 0, 0);
}

// s_waitcnt with vmcnt=N, lgkmcnt/expcnt = don't-care
template<int N> static __device__ __forceinline__ void waitcnt_vm() {
    __builtin_amdgcn_s_waitcnt((N & 0xF) | (7 << 4) | (0xF << 8) | (((N >> 4) & 3) << 14));
}

// ---------------------------------------------------------------- fused one-shot prep
// Jobs (flat index space):
//   [0, 589824)            : in_proj_w  f32x4 -> bf16x4
//   [589824, 884736)       : out_proj_w f32x4 -> bf16x4
//   [884736, 1364736)      : embed      f32x4 -> bf16x4
//   [1364736, 4117248)     : wf element (build fused proj weight)
//   [4117248, 4903680)     : embed gather -> x (float4 per job)
__global__ __launch_bounds__(256)
void prep_k(const float* __restrict__ inw, const float* __restrict__ outw,
            const float* __restrict__ emb, const float* __restrict__ xpw,
            const float* __restrict__ dtw, const int* __restrict__ tokens,
            ushort* __restrict__ inw_b, ushort* __restrict__ outw_b,
            ushort* __restrict__ emb_b, ushort* __restrict__ wf,
            float* __restrict__ x)
{
    int idx = blockIdx.x * 256 + threadIdx.x;
    if (idx < 589824) {
        float4 v = reinterpret_cast<const float4*>(inw)[idx];
        ushort4 o; o.x=f2b(v.x); o.y=f2b(v.y); o.z=f2b(v.z); o.w=f2b(v.w);
        reinterpret_cast<ushort4*>(inw_b)[idx] = o;
    } else if (idx < 884736) {
        int i = idx - 589824;
        float4 v = reinterpret_cast<const float4*>(outw)[i];
        ushort4 o; o.x=f2b(v.x); o.y=f2b(v.y); o.z=f2b(v.z); o.w=f2b(v.w);
        reinterpret_cast<ushort4*>(outw_b)[i] = o;
    } else if (idx < 1364736) {
        int i = idx - 884736;
        float4 v = reinterpret_cast<const float4*>(emb)[i];
        ushort4 o; o.x=f2b(v.x); o.y=f2b(v.y); o.z=f2b(v.z); o.w=f2b(v.w);
        reinterpret_cast<ushort4*>(emb_b)[i] = o;
    } else if (idx < 4117248) {
        int i = idx - 1364736;                      // 4*896*768 elements
        int l = i / (896*768); int rk = i % (896*768);
        int r = rk / 768, k = rk % 768;
        float v = 0.f;
        if (r < 768) {
            const float* dr = dtw + ((size_t)l*768 + r)*24;
            const float* xc = xpw + (size_t)l*56*768 + k;
            #pragma unroll
            for (int q = 0; q < 24; ++q) v += dr[q] * xc[(size_t)q*768];
        } else if (r < 800) {
            v = xpw[((size_t)l*56 + 24 + (r-768))*768 + k];
        }
        wf[i] = f2b(v);
    } else {
        int i = idx - 4117248;                      // ROWS*96 float4 jobs
        int row = i / 96, c4 = i % 96;
        int tok = tokens[row];
        reinterpret_cast<float4*>(x)[(size_t)row * 96 + c4] =
            reinterpret_cast<const float4*>(emb)[(size_t)tok * 96 + c4];
    }
}

// ---------------------------------------------------------------- rmsnorm -> bf16
__global__ __launch_bounds__(256)
void rmsnorm_k(const float* __restrict__ xin, const float* __restrict__ w,
               ushort* __restrict__ xout)
{
    int row  = blockIdx.x * 4 + (threadIdx.x >> 6);
    int lane = threadIdx.x & 63;
    const float* xr = xin + (size_t)row * D_MODEL;
    float v[6]; float ss = 0.f;
    #pragma unroll
    for (int j = 0; j < 6; ++j) { v[j] = xr[lane + 64*j]; ss += v[j]*v[j]; }
    #pragma unroll
    for (int m = 32; m; m >>= 1) ss += __shfl_xor(ss, m, 64);
    float r = rsqrtf(ss * (1.f/D_MODEL) + 1e-5f);
    ushort* yo = xout + (size_t)row * D_MODEL;
    #pragma unroll
    for (int j = 0; j < 6; ++j) yo[lane + 64*j] = f2b(v[j] * w[lane + 64*j] * r);
}

// ---------------------------------------------------------------- conv1d + silu -> bf16
// 8 rows x 4 channels per thread, rolling window (read amplification 11/8).
__global__ __launch_bounds__(256)
void conv_silu_k(const ushort* __restrict__ xz_b, const float* __restrict__ cw,
                 const float* __restrict__ cb, ushort* __restrict__ xout_b)
{
    int idx = blockIdx.x * 256 + threadIdx.x;       // (ROWS/8) * 192
    int e4  = idx % 192;                            // quad of channels
    int rg  = idx / 192;                            // 8-row group
    int e   = e4 * 4;
    int row0 = rg * 8;
    bool seq_start = (row0 & (SEQ - 1)) == 0;

    float4 w0 = reinterpret_cast<const float4*>(cw)[e4*4 + 0];   // cw[e+0][0..3]
    float4 w1 = reinterpret_cast<const float4*>(cw)[e4*4 + 1];
    float4 w2 = reinterpret_cast<const float4*>(cw)[e4*4 + 2];
    float4 w3 = reinterpret_cast<const float4*>(cw)[e4*4 + 3];
    float4 bv = reinterpret_cast<const float4*>(cb)[e4];

    // window: p1 = row-1, p2 = row-2, p3 = row-3 (f32x4 over the 4 channels)
    float p1x=0,p1y=0,p1z=0,p1w=0, p2x=0,p2y=0,p2z=0,p2w=0, p3x=0,p3y=0,p3z=0,p3w=0;
    if (!seq_start) {
        ushort4 a = *reinterpret_cast<const ushort4*>(&xz_b[(size_t)(row0-1) * (2*D_INNER) + e]);
        ushort4 b = *reinterpret_cast<const ushort4*>(&xz_b[(size_t)(row0-2) * (2*D_INNER) + e]);
        ushort4 c = *reinterpret_cast<const ushort4*>(&xz_b[(size_t)(row0-3) * (2*D_INNER) + e]);
        p1x=b2f(a.x); p1y=b2f(a.y); p1z=b2f(a.z); p1w=b2f(a.w);
        p2x=b2f(b.x); p2y=b2f(b.y); p2z=b2f(b.z); p2w=b2f(b.w);
        p3x=b2f(c.x); p3y=b2f(c.y); p3z=b2f(c.z); p3w=b2f(c.w);
    }

    #pragma unroll
    for (int j = 0; j < 8; ++j) {
        ushort4 v = *reinterpret_cast<const ushort4*>(
            &xz_b[(size_t)(row0 + j) * (2*D_INNER) + e]);
        float cx = b2f(v.x), cy = b2f(v.y), cz = b2f(v.z), cw4 = b2f(v.w);
        float a0 = bv.x + w0.w*cx + w0.z*p1x + w0.y*p2x + w0.x*p3x;
        float a1 = bv.y + w1.w*cy + w1.z*p1y + w1.y*p2y + w1.x*p3y;
        float a2 = bv.z + w2.w*cz + w2.z*p1z + w2.y*p2z + w2.x*p3z;
        float a3 = bv.w + w3.w*cw4 + w3.z*p1w + w3.y*p2w + w3.x*p3w;
        ushort4 o;
        o.x = f2b(a0 / (1.f + __expf(-a0)));
        o.y = f2b(a1 / (1.f + __expf(-a1)));
        o.z = f2b(a2 / (1.f + __expf(-a2)));
        o.w = f2b(a3 / (1.f + __expf(-a3)));
        *reinterpret_cast<ushort4*>(&xout_b[(size_t)(row0 + j) * D_INNER + e]) = o;
        p3x=p2x; p3y=p2y; p3z=p2z; p3w=p2w;
        p2x=p1x; p2y=p1y; p2z=p1z; p2w=p1w;
        p1x=cx;  p1y=cy;  p1z=cz;  p1w=cw4;
    }
}

// ---------------------------------------------------------------- LDS-staged MFMA GEMM
// C[M,N](f32) = A[M,K](bf16) @ B[N,K](bf16)^T.
// 3-buf counted-vmcnt pipeline; swapped-operand MFMA (lane holds C row m = l15,
// 4 consecutive cols); XOR-swizzled LDS (both-sides).
// EPI: 0 store f32x4 (C) | 2 C += (f32x4 RMW) | 4 store bf16x4 (Cb, ldc)
//      5 fused-proj: n<768 -> softplus(v+bias[n]) -> bf16x4 Cb (ldc=768) ;
//                    768<=n<800 -> f32x4 -> C[m*32 + n-768]  (bc buffer)
template<int TM, int TN, int EPI>
__global__ __launch_bounds__(256)
void gemm_lds(const ushort* __restrict__ A, int lda,
              const ushort* __restrict__ B, int ldb,
              float* __restrict__ C, int ldc,
              ushort* __restrict__ Cb, const float* __restrict__ bias,
              int N, int K)
{
    constexpr int FM = TM / 32, FN = TN / 32;
    constexpr int LPT = TM/64 + TN/64;
    __shared__ alignas(16) ushort As[3][TM * 32];
    __shared__ alignas(16) ushort Bs[3][TN * 32];
    int tid = threadIdx.x, w = tid >> 6, l = tid & 63;
    int wr = w >> 1, wc = w & 1;
    int row0 = blockIdx.y * TM, col0 = blockIdx.x * TN;
    int l15 = l & 15, g = l >> 4;
    int sr = l >> 2, sp = l & 3;

    f32x4 acc[FM][FN] = {};

    auto stage = [&](int buf, int k0) {
        #pragma unroll
        for (int j = 0; j < TM/64; ++j) {
            int ai = w * (TM/64) + j;
            int r  = ai * 16 + sr;
            int s  = sp ^ ((r >> 1) & 3);
            gl_lds16(&A[(size_t)(row0 + r) * lda + k0 + s*8], &As[buf][ai * 512]);
        }
        #pragma unroll
        for (int j = 0; j < TN/64; ++j) {
            int bi = w * (TN/64) + j;
            int r  = bi * 16 + sr;
            int s  = sp ^ ((r >> 1) & 3);
            gl_lds16(&B[(size_t)(col0 + r) * ldb + k0 + s*8], &Bs[buf][bi * 512]);
        }
    };

    int nk = K >> 5;
    stage(0, 0);
    if (nk > 1) stage(1, 32);

    int cur = 0, sbuf = 2;
    for (int t = 0; t < nk; ++t) {
        if (t < nk - 1) waitcnt_vm<LPT>();
        else            waitcnt_vm<0>();
        __builtin_amdgcn_sched_barrier(0);
        __builtin_amdgcn_s_barrier();
        __builtin_amdgcn_sched_barrier(0);
        if (t + 2 < nk) stage(sbuf, (t + 2) << 5);
        __builtin_amdgcn_sched_barrier(0);

        bf16x8 af[FM], bfr[FN];
        #pragma unroll
        for (int i = 0; i < FM; ++i) {
            int r = wr * (TM/2) + i*16 + l15;
            int p = g ^ ((r >> 1) & 3);
            af[i] = *reinterpret_cast<const bf16x8*>(&As[cur][r*32 + p*8]);
        }
        #pragma unroll
        for (int i = 0; i < FN; ++i) {
            int r = wc * (TN/2) + i*16 + l15;
            int p = g ^ ((r >> 1) & 3);
            bfr[i] = *reinterpret_cast<const bf16x8*>(&Bs[cur][r*32 + p*8]);
        }
        #pragma unroll
        for (int i = 0; i < FM; ++i)
            #pragma unroll
            for (int jj = 0; jj < FN; ++jj)
                acc[i][jj] = __builtin_amdgcn_mfma_f32_16x16x32_bf16(bfr[jj], af[i], acc[i][jj], 0, 0, 0);

        cur  = (cur  == 2) ? 0 : cur + 1;
        sbuf = (sbuf == 2) ? 0 : sbuf + 1;
    }

    #pragma unroll
    for (int i = 0; i < FM; ++i) {
        int m = row0 + wr * (TM/2) + i*16 + l15;
        #pragma unroll
        for (int jj = 0; jj < FN; ++jj) {
            int n0 = col0 + wc * (TN/2) + jj*16 + g*4;
            if (n0 < N) {
                f32x4 v = acc[i][jj];
                if (EPI == 2) {
                    float4* p = reinterpret_cast<float4*>(&C[(size_t)m * ldc + n0]);
                    float4 o = *p;
                    o.x += v[0]; o.y += v[1]; o.z += v[2]; o.w += v[3];
                    *p = o;
                } else if (EPI == 4) {
                    ushort4 o;
                    o.x = f2b(v[0]); o.y = f2b(v[1]); o.z = f2b(v[2]); o.w = f2b(v[3]);
                    *reinterpret_cast<ushort4*>(&Cb[(size_t)m * ldc + n0]) = o;
                } else if (EPI == 5) {
                    if (n0 < 768) {
                        float4 bv = *reinterpret_cast<const float4*>(&bias[n0]);
                        ushort4 o;
                        o.x = f2b(softplus_f(v[0] + bv.x));
                        o.y = f2b(softplus_f(v[1] + bv.y));
                        o.z = f2b(softplus_f(v[2] + bv.z));
                        o.w = f2b(softplus_f(v[3] + bv.w));
                        *reinterpret_cast<ushort4*>(&Cb[(size_t)m * ldc + n0]) = o;  // dt bf16, ldc=768
                    } else {
                        float4 o; o.x = v[0]; o.y = v[1]; o.z = v[2]; o.w = v[3];
                        *reinterpret_cast<float4*>(&C[(size_t)m * 32 + (n0 - 768)]) = o;  // bc f32
                    }
                } else {
                    float4 o; o.x = v[0]; o.y = v[1]; o.z = v[2]; o.w = v[3];
                    *reinterpret_cast<float4*>(&C[(size_t)m * ldc + n0]) = o;
                }
            }
        }
    }
}

// ---------------------------------------------------------------- chunked scan
// Thread <-> (b, chunk, e); all 16 states in registers.
// h_end/decay/h_init layout: [b][e][n][c]  (c innermost, NCHUNK=64), ALL bf16.
// bc layout: [row][32]  (B: 0..15, C: 16..31), f32.  dt is bf16.

__global__ __launch_bounds__(256)
void scan_p1(const ushort* __restrict__ dtb, const ushort* __restrict__ xin_b,
             const float* __restrict__ bc, const float* __restrict__ A_log,
             ushort* __restrict__ h_end, ushort* __restrict__ decay)
{
    __shared__ float Bs[CLEN][16];
    int b = blockIdx.z, c = blockIdx.y;
    int e = blockIdx.x * 256 + threadIdx.x;
    size_t r0 = (size_t)b * SEQ + (size_t)c * CLEN;

    for (int i = threadIdx.x; i < CLEN*16; i += 256) {
        int l = i >> 4, n = i & 15;
        Bs[l][n] = bc[(r0 + l) * 32 + n];
    }
    __syncthreads();

    float a[16];
    const float4* ap = reinterpret_cast<const float4*>(A_log + e * D_STATE);
    #pragma unroll
    for (int q = 0; q < 4; ++q) {
        float4 av = ap[q];
        a[q*4+0] = -__expf(av.x); a[q*4+1] = -__expf(av.y);
        a[q*4+2] = -__expf(av.z); a[q*4+3] = -__expf(av.w);
    }

    const ushort* pdt = dtb   + r0 * D_INNER + e;
    const ushort* px  = xin_b + r0 * D_INNER + e;
    float h[16];
    #pragma unroll
    for (int n = 0; n < 16; ++n) h[n] = 0.f;
    float S = 0.f;
    float dtv = b2f(pdt[0]), xv = b2f(px[0]);

    for (int l = 0; l < CLEN; ++l) {
        float dtn = 0.f, xn2 = 0.f;
        if (l + 1 < CLEN) {
            dtn = b2f(pdt[(size_t)(l+1) * D_INNER]);
            xn2 = b2f(px [(size_t)(l+1) * D_INNER]);
        }
        float dtx = dtv * xv;
        S += dtv;
        const float4* br = reinterpret_cast<const float4*>(&Bs[l][0]);
        float4 B0 = br[0], B1 = br[1], B2 = br[2], B3 = br[3];
        float Bv[16] = {B0.x,B0.y,B0.z,B0.w, B1.x,B1.y,B1.z,B1.w,
                        B2.x,B2.y,B2.z,B2.w, B3.x,B3.y,B3.z,B3.w};
        #pragma unroll
        for (int n = 0; n < 16; ++n) {
            float ex = __expf(dtv * a[n]);
            h[n] = h[n] * ex + dtx * Bv[n];
        }
        dtv = dtn; xv = xn2;
    }

    size_t base = (((size_t)b * D_INNER + e) * D_STATE) * NCHUNK + c;
    #pragma unroll
    for (int n = 0; n < 16; ++n) {
        h_end[base + (size_t)n * NCHUNK] = f2b(h[n]);
        decay[base + (size_t)n * NCHUNK] = f2b(__expf(a[n] * S));
    }
}

// Pass 2: wave-parallel (Hillis-Steele) chunk combine. One wave per (b,e,n);
// lane = chunk. Pair (d,v): h_out = v + d*h_in; compose left-to-right.
__global__ __launch_bounds__(256)
void scan_p2(const ushort* __restrict__ h_end, const ushort* __restrict__ decay,
             ushort* __restrict__ h_init)
{
    int wid  = (blockIdx.x * 256 + threadIdx.x) >> 6;   // (b,e,n) flat
    int lane = threadIdx.x & 63;
    size_t base = (size_t)wid * NCHUNK;
    float d = b2f(decay[base + lane]);
    float v = b2f(h_end[base + lane]);
    #pragma unroll
    for (int off = 1; off < 64; off <<= 1) {
        float dp = __shfl_up(d, off, 64);
        float vp = __shfl_up(v, off, 64);
        if (lane >= off) { v = fmaf(d, vp, v); d *= dp; }
    }
    float hi = __shfl_up(v, 1, 64);
    if (lane == 0) hi = 0.f;
    h_init[base + lane] = f2b(hi);
}

// Pass 3: re-scan each chunk from h_init; y + D-skip + gate -> bf16
__global__ __launch_bounds__(256)
void scan_p3(const ushort* __restrict__ dtb, const ushort* __restrict__ xin_b,
             const ushort* __restrict__ xz_b, const float* __restrict__ bc,
             const float* __restrict__ A_log, const float* __restrict__ Dp,
             const ushort* __restrict__ h_init, ushort* __restrict__ y)
{
    __shared__ float BCs[CLEN][32];
    int b = blockIdx.z, c = blockIdx.y;
    int e = blockIdx.x * 256 + threadIdx.x;
    size_t r0 = (size_t)b * SEQ + (size_t)c * CLEN;

    for (int i = threadIdx.x; i < CLEN*32; i += 256) {
        int l = i >> 5, r = i & 31;
        BCs[l][r] = bc[(r0 + l) * 32 + r];
    }
    __syncthreads();

    float a[16];
    const float4* ap = reinterpret_cast<const float4*>(A_log + e * D_STATE);
    #pragma unroll
    for (int q = 0; q < 4; ++q) {
        float4 av = ap[q];
        a[q*4+0] = -__expf(av.x); a[q*4+1] = -__expf(av.y);
        a[q*4+2] = -__expf(av.z); a[q*4+3] = -__expf(av.w);
    }
    float dskip = Dp[e];

    float h[16];
    size_t hbase = (((size_t)b * D_INNER + e) * D_STATE) * NCHUNK + c;
    #pragma unroll
    for (int n = 0; n < 16; ++n) h[n] = b2f(h_init[hbase + (size_t)n * NCHUNK]);

    const ushort* pdt = dtb   + r0 * D_INNER + e;
    const ushort* px  = xin_b + r0 * D_INNER + e;
    const ushort* pz  = xz_b  + r0 * (2*D_INNER) + D_INNER + e;
    ushort*       py  = y     + r0 * D_INNER + e;

    float dtv = b2f(pdt[0]), xv = b2f(px[0]), zv = b2f(pz[0]);

    for (int l = 0; l < CLEN; ++l) {
        float dtn = 0.f, xn2 = 0.f, zn = 0.f;
        if (l + 1 < CLEN) {
            dtn = b2f(pdt[(size_t)(l+1) * D_INNER]);
            xn2 = b2f(px [(size_t)(l+1) * D_INNER]);
            zn  = b2f(pz [(size_t)(l+1) * (2*D_INNER)]);
        }
        float dtx = dtv * xv;
        const float4* br = reinterpret_cast<const float4*>(&BCs[l][0]);
        float4 B0 = br[0], B1 = br[1], B2 = br[2], B3 = br[3];
        float Bv[16] = {B0.x,B0.y,B0.z,B0.w, B1.x,B1.y,B1.z,B1.w,
                        B2.x,B2.y,B2.z,B2.w, B3.x,B3.y,B3.z,B3.w};
        #pragma unroll
        for (int n = 0; n < 16; ++n) {
            float ex = __expf(dtv * a[n]);
            h[n] = h[n] * ex + dtx * Bv[n];
        }
        float4 C0 = br[4], C1 = br[5], C2 = br[6], C3 = br[7];
        float Cv[16] = {C0.x,C0.y,C0.z,C0.w, C1.x,C1.y,C1.z,C1.w,
                        C2.x,C2.y,C2.z,C2.w, C3.x,C3.y,C3.z,C3.w};
        float yv = 0.f;
        #pragma unroll
        for (int n = 0; n < 16; ++n) yv += h[n] * Cv[n];

        float g = zv / (1.f + __expf(-zv));         // silu(z)
        py[(size_t)l * D_INNER] = f2b((yv + xv * dskip) * g);

        dtv = dtn; xv = xn2; zv = zn;
    }
}

// ---------------------------------------------------------------- launch
extern "C" void kernel_launch(void* const* d_in, const int* in_sizes, int n_in,
                              void* d_out, int out_size, void* d_ws, size_t ws_size,
                              hipStream_t stream)
{
    const int*   tokens       = (const int*)  d_in[0];
    const float* embed        = (const float*)d_in[1];
    const float* norm_w       = (const float*)d_in[2];
    const float* in_proj_w    = (const float*)d_in[3];
    const float* conv_w       = (const float*)d_in[4];
    const float* conv_b       = (const float*)d_in[5];
    const float* x_proj_w     = (const float*)d_in[6];
    const float* dt_proj_w    = (const float*)d_in[7];
    const float* dt_proj_b    = (const float*)d_in[8];
    const float* A_log        = (const float*)d_in[9];
    const float* D_param      = (const float*)d_in[10];
    const float* out_proj_w   = (const float*)d_in[11];
    const float* final_norm_w = (const float*)d_in[12];
    float* out = (float*)d_out;

    // ---- workspace map (float offsets), ~36 MB
    float* ws = (float*)d_ws;
    float*  x      = ws;                          // 3,145,728 f
    ushort* inw_b  = (ushort*)(ws + 3145728);     // 2,359,296 us -> f 4,325,376
    ushort* outw_b = (ushort*)(ws + 4325376);     // 1,179,648 us -> 4,915,200
    ushort* emb_b  = (ushort*)(ws + 4915200);     // 5120*384 us  -> 5,898,240 (rows>=5000 junk, never stored)
    ushort* wf_b   = (ushort*)(ws + 5898240);     // 4*896*768 us -> 7,274,496
    float*  bc     = ws + 7274496;                // 262,144 f    -> 7,536,640
    ushort* xn_b   = (ushort*)(ws + 7536640);     // 3,145,728 us -> 9,109,504

    // ---- big scratch in d_out (40,960,000 floats; all dead before lm_head)
    ushort* xz_b   = (ushort*)out;                // 12,582,912 us -> f 6,291,456
    ushort* dtb    = (ushort*)(out + 6291456);    // 6,291,456 us -> 9,437,184
    ushort* y_b    = (ushort*)(out + 9437184);    // -> 12,582,912
    ushort* xin_b  = (ushort*)(out + 12582912);   // -> 15,728,640
    ushort* h_end  = (ushort*)(out + 15728640);   // 3,145,728 us -> 17,301,504
    ushort* decay  = (ushort*)(out + 17301504);   // -> 18,874,368
    ushort* h_init = (ushort*)(out + 18874368);   // -> 20,447,232 (< 40,960,000)

    dim3 blk(256);

    // fused one-shot prep (5 jobs in one node); 4,903,680 flat jobs
    prep_k<<<19155, blk, 0, stream>>>(in_proj_w, out_proj_w, embed, x_proj_w,
                                      dt_proj_w, tokens,
                                      inw_b, outw_b, emb_b, wf_b, x);

    for (int i = 0; i < N_LAYER; ++i) {
        rmsnorm_k<<<ROWS/4, blk, 0, stream>>>(x, norm_w + i*D_MODEL, xn_b);
        // in_proj: 8192 x 1536 x 384 -> bf16 xz
        gemm_lds<128,128,4><<<dim3(12, 64), blk, 0, stream>>>(
            xn_b, D_MODEL, inw_b + (size_t)i*2*D_INNER*D_MODEL, D_MODEL,
            nullptr, 2*D_INNER, xz_b, nullptr, 2*D_INNER, D_MODEL);
        // conv + silu -> xin bf16 (8 rows x 4 ch per thread, rolling window)
        conv_silu_k<<<ROWS/8*192/256, blk, 0, stream>>>(
            xz_b, conv_w + i*D_INNER*D_CONV, conv_b + i*D_INNER, xin_b);
        // fused x_proj+dt_proj: 8192 x 800(pad 832) x 768
        //   n<768: dt = softplus(.+bias) -> dtb (bf16) ; n in [768,800) -> bc (f32)
        gemm_lds<128,64,5><<<dim3(13, 64), blk, 0, stream>>>(
            xin_b, D_INNER, wf_b + (size_t)i*896*D_INNER, D_INNER,
            bc, D_INNER, dtb, dt_proj_b + i*D_INNER, 800, D_INNER);
        // chunked selective scan (bf16 chunk-state)
        scan_p1<<<dim3(3, NCHUNK, BATCH), blk, 0, stream>>>(
            dtb, xin_b, bc, A_log + (size_t)i*D_INNER*D_STATE, h_end, decay);
        scan_p2<<<BATCH*D_INNER*D_STATE/4, blk, 0, stream>>>(h_end, decay, h_init);
        scan_p3<<<dim3(3, NCHUNK, BATCH), blk, 0, stream>>>(
            dtb, xin_b, xz_b, bc, A_log + (size_t)i*D_INNER*D_STATE,
            D_param + i*D_INNER, h_init, y_b);
        // out_proj + residual: 8192 x 384 x 768, x += ... (float4 RMW)
        gemm_lds<64,64,2><<<dim3(6, 128), blk, 0, stream>>>(
            y_b, D_INNER, outw_b + (size_t)i*D_MODEL*D_INNER, D_INNER,
            x, D_MODEL, nullptr, nullptr, D_MODEL, D_INNER);
    }

    rmsnorm_k<<<ROWS/4, blk, 0, stream>>>(x, final_norm_w, xn_b);
    // lm_head: 8192 x 5000 x 384 (overwrites ALL of d_out; float4 stores)
    gemm_lds<128,128,0><<<dim3(40, 64), blk, 0, stream>>>(
        xn_b, D_MODEL, emb_b, D_MODEL, out, VOCAB, nullptr, nullptr, VOCAB, D_MODEL);
}